// Round 15
// baseline (43.838 us; speedup 1.0000x reference)
//
#include <hip/hip_runtime.h>
#include <math.h>

#define N_S 1024
#define XD  768
#define LOW 300
#define KP  320     // f16 k-padding
#define KP2 160     // u32 (h2) per row

typedef _Float16 h2  __attribute__((ext_vector_type(2)));
typedef __fp16   g2  __attribute__((ext_vector_type(2)));
typedef _Float16 v8h __attribute__((ext_vector_type(8)));
typedef float    f4  __attribute__((ext_vector_type(4)));

union U32H2 { unsigned int u; h2 h; };
__device__ inline h2 u2h(unsigned int v){ U32H2 t; t.u = v; return t.h; }
__device__ inline unsigned int pk(float a, float b){
    g2 t = __builtin_amdgcn_cvt_pkrtz(a, b);
    return __builtin_bit_cast(unsigned int, t);
}
union U4V8 { uint4 u; v8h v; };

// ---------------------------------------------------------------------------
// Kernel 1: projection GEMM via MFMA f16 (r12-verified, unchanged). 320 jobs.
// Also zeroes partsum[1024] and cnt (visible to kernel 2 via stream order).
// ---------------------------------------------------------------------------
__global__ __launch_bounds__(512)
void gemm_h(const float* __restrict__ x, const float* __restrict__ y,
            const float* __restrict__ W1, const float* __restrict__ b1g,
            unsigned int* __restrict__ hx_h, unsigned int* __restrict__ hy_h,
            float* __restrict__ partsum, unsigned int* __restrict__ cnt)
{
    __shared__ unsigned int As[2][32][36];
    __shared__ unsigned int Bs[2][64][36];

    const int tid = threadIdx.x;
    const int job = blockIdx.x;
    if (job < 256 && tid < 4) partsum[job * 4 + tid] = 0.f;
    if (job == 0 && tid == 4) cnt[0] = 0u;

    const int which = job >= 160;
    const int t = which ? job - 160 : job;
    const int n0 = (t % 5) * 64;
    const int r0 = (t / 5) * 32;
    const float* A = which ? y : x;
    const float* W = W1 + (size_t)which * XD * LOW;
    _Float16* outh = (_Float16*)(which ? hy_h : hx_h);

    const int w = tid >> 6, l = tid & 63;
    const int wm = w >> 2, wn = w & 3;         // 2M x 4N
    const int lr = l & 15, lg = l >> 4;

    const int arow = tid >> 4, aq = tid & 15;  // A staging: 32 rows x 16 f4
    const int bn = tid & 63, bms = tid >> 6;   // B staging: 64 ncols x 8 m-grp
    const bool bin = (n0 + bn) < LOW;

    f4 acc = {};
    float4 a0; float bw[8];
    a0 = *(const float4*)&A[(size_t)(r0 + arow) * XD + aq * 4];
    #pragma unroll
    for (int s = 0; s < 8; ++s)
        bw[s] = bin ? W[(size_t)(bms * 8 + s) * LOW + n0 + bn] : 0.f;

    const int NC = XD / 64;                    // 12
    for (int c = 0; c < NC; ++c) {
        const int buf = c & 1;
        *(uint2*)&As[buf][arow][aq * 2] = make_uint2(pk(a0.x, a0.y), pk(a0.z, a0.w));
        *(uint4*)&Bs[buf][bn][bms * 4] =
            uint4{ pk(bw[0],bw[1]), pk(bw[2],bw[3]), pk(bw[4],bw[5]), pk(bw[6],bw[7]) };
        __syncthreads();
        if (c + 1 < NC) {
            const int kb = (c + 1) * 64;
            a0 = *(const float4*)&A[(size_t)(r0 + arow) * XD + kb + aq * 4];
            #pragma unroll
            for (int s = 0; s < 8; ++s)
                bw[s] = bin ? W[(size_t)(kb + bms * 8 + s) * LOW + n0 + bn] : 0.f;
        }
        #pragma unroll
        for (int ks = 0; ks < 2; ++ks) {
            const int ko = ks * 16 + lg * 4;
            U4V8 af; af.u = *(const uint4*)&As[buf][wm * 16 + lr][ko];
            U4V8 bf; bf.u = *(const uint4*)&Bs[buf][wn * 16 + lr][ko];
            acc = __builtin_amdgcn_mfma_f32_16x16x32_f16(af.v, bf.v, acc, 0, 0, 0);
        }
    }

    // D: col = l&15, row = 4*(l>>4)+r  (m89-verified)
    const int col = n0 + wn * 16 + lr;
    const float b1v = (which && col < LOW) ? b1g[col] : 0.f;
    #pragma unroll
    for (int r = 0; r < 4; ++r) {
        const int row = r0 + wm * 16 + lg * 4 + r;
        outh[(size_t)row * KP + col] = (_Float16)(acc[r] + b1v);
    }
}

// ---------------------------------------------------------------------------
// Kernel 2: pairwise critic. 32i x 64j tile, 4i x 4j x k-half per thread,
// natural [row][k] LDS (coalesced staging, no transpose), Hx slot-swizzled
// (slot = t ^ (tx&7)) for conflict-free 16-row b128 reads, v_pk_fma_f16
// accumulation (full-rate packed) with f32 dump every 32 k.
//   s[i][j] = sum_k relu(hy[i,k]+hx[j,k])*w2[k] + b2
//   partsum[i] += sum_j e^s  (exp(softplus)=1+e^s);  diag[i]=softplus(s[i,i])
// 512 blocks (XCD-swizzled), 256 thr, 2 blk/CU. Atomic finish (r12-verified).
// ---------------------------------------------------------------------------
__global__ __launch_bounds__(256)
void pair_kernel(const unsigned int* __restrict__ hx_h, const unsigned int* __restrict__ hy_h,
                 const float* __restrict__ W2, const float* __restrict__ b2,
                 float* __restrict__ partsum, float* __restrict__ diag,
                 unsigned int* __restrict__ cnt, float* __restrict__ out)
{
    // XCD-aware bijective swizzle (512 % 8 == 0)
    const int b0 = blockIdx.x;
    const int bs = (b0 & 7) * 64 + (b0 >> 3);
    const int jb = bs & 15, ib = bs >> 4;      // 16 j-tiles x 32 i-tiles
    const int j0 = jb * 64, i0 = ib * 32;

    __shared__ unsigned int Hy[32][160];       // [i][k/2], linear
    __shared__ unsigned int Hx[64][160];       // [j][k/2], slot-swizzled
    __shared__ unsigned int w2s[KP2];          // linear (uniform reads)
    __shared__ unsigned int lastFlag;
    __shared__ float ssum[4];

    const int tid = threadIdx.x;

    // ---- stage Hy: straight coalesced copy (5 uint4/thread) ----
    {
        const int r = tid >> 3, sq = tid & 7;
        const unsigned int* sy = &hy_h[(size_t)(i0 + r) * KP2];
        #pragma unroll
        for (int e = 0; e < 5; ++e) {
            const int s = sq + 8 * e;
            *(uint4*)&Hy[r][s * 4] = *(const uint4*)&sy[s * 4];
        }
    }
    // ---- stage Hx: coalesced src, swizzled dst slot (10 uint4/thread) ----
    {
        #pragma unroll
        for (int rp = 0; rp < 2; ++rp) {
            const int r = (tid >> 3) + 32 * rp, sq = tid & 7;
            const unsigned int* sx = &hx_h[(size_t)(j0 + r) * KP2];
            const int swz = (r >> 2) & 7;
            #pragma unroll
            for (int e = 0; e < 5; ++e) {
                const int s = sq + 8 * e;
                *(uint4*)&Hx[r][(s ^ swz) * 4] = *(const uint4*)&sx[s * 4];
            }
        }
    }
    if (tid < KP2) {
        int k = tid * 2;
        float w0 = (k < LOW) ? W2[k] : 0.f;
        float w1 = (k + 1 < LOW) ? W2[k + 1] : 0.f;
        w2s[tid] = pk(w0, w1);
    }
    __syncthreads();

    const int tx = tid & 15;           // j = j0 + tx*4 + q
    const int kh = (tid >> 4) & 1;     // k-half: t in [kh*20, kh*20+20)
    const int iy = tid >> 5;           // i = i0 + iy*4 + r
    const int xsw = tx & 7;            // Hx slot swizzle for this thread

    float accf[4][4] = {};
    const h2 hz = h2{(_Float16)0.f, (_Float16)0.f};
    const int tb = kh * 20;

    for (int tc = 0; tc < 5; ++tc) {             // 5 chunks x 4 t-iters (32k)
        h2 acch[4][4];
        #pragma unroll
        for (int r = 0; r < 4; ++r)
            #pragma unroll
            for (int q = 0; q < 4; ++q) acch[r][q] = hz;

        #pragma unroll
        for (int ti = 0; ti < 4; ++ti) {
            const int t = tb + tc * 4 + ti;
            uint4 ya[4], xb[4];
            #pragma unroll
            for (int r = 0; r < 4; ++r)
                ya[r] = *(const uint4*)&Hy[iy * 4 + r][t * 4];
            const int sx = (t ^ xsw) * 4;
            #pragma unroll
            for (int q = 0; q < 4; ++q)
                xb[q] = *(const uint4*)&Hx[tx * 4 + q][sx];
            const uint4 wv = *(const uint4*)&w2s[t * 4];   // uniform
            const unsigned int wve[4] = {wv.x, wv.y, wv.z, wv.w};
            #pragma unroll
            for (int e = 0; e < 4; ++e) {
                const h2 w = u2h(wve[e]);
                const unsigned int yae[4] = {ya[0][e], ya[1][e], ya[2][e], ya[3][e]};
                const unsigned int xbe[4] = {xb[0][e], xb[1][e], xb[2][e], xb[3][e]};
                #pragma unroll
                for (int r = 0; r < 4; ++r) {
                    const h2 a = u2h(yae[r]);
                    #pragma unroll
                    for (int q = 0; q < 4; ++q) {
                        h2 z = __builtin_elementwise_max(a + u2h(xbe[q]), hz);
                        acch[r][q] = __builtin_elementwise_fma(z, w, acch[r][q]);
                    }
                }
            }
        }
        #pragma unroll
        for (int r = 0; r < 4; ++r)
            #pragma unroll
            for (int q = 0; q < 4; ++q)
                accf[r][q] += (float)acch[r][q][0] + (float)acch[r][q][1];
    }

    // combine the two k-halves (partner lane differs in bit 4)
    #pragma unroll
    for (int r = 0; r < 4; ++r)
        #pragma unroll
        for (int q = 0; q < 4; ++q)
            accf[r][q] += __shfl_xor(accf[r][q], 16, 64);

    const float b2v = b2[0];
    #pragma unroll
    for (int r = 0; r < 4; ++r) {
        const int row = i0 + iy * 4 + r;
        float es = 0.f;
        #pragma unroll
        for (int q = 0; q < 4; ++q) {
            const float s = accf[r][q] + b2v;
            es += __expf(s);                     // exp(softplus) = 1 + e^s
            const int col = j0 + tx * 4 + q;
            if (col == row)
                atomicExch(&diag[row],
                           fmaxf(s, 0.f) + __logf(1.f + __expf(-fabsf(s))));
        }
        #pragma unroll
        for (int o = 1; o <= 8; o <<= 1) es += __shfl_xor(es, o, 64);
        if ((tid & 31) == 0) atomicAdd(&partsum[row], es);
    }

    // ---- completion: drain atomics, count blocks, last block reduces ----
    asm volatile("s_waitcnt vmcnt(0)" ::: "memory");
    __syncthreads();
    if (tid == 0) lastFlag = (atomicAdd(cnt, 1u) == 511u) ? 1u : 0u;
    __syncthreads();
    if (!lastFlag) return;

    float csum = 0.f;
    #pragma unroll
    for (int g = 0; g < 4; ++g) {
        const int row = g * 256 + tid;
        const float ps = atomicAdd(&partsum[row], 0.f);   // coherent read
        const float dg = atomicAdd(&diag[row], 0.f);      // coherent read
        csum += dg - __logf((float)N_S + ps);
    }
    #pragma unroll
    for (int o = 32; o > 0; o >>= 1) csum += __shfl_xor(csum, o, 64);
    if ((tid & 63) == 0) ssum[tid >> 6] = csum;
    __syncthreads();
    if (tid == 0)
        out[0] = (ssum[0] + ssum[1] + ssum[2] + ssum[3]) * (1.0f / N_S)
               - logf((float)N_S);
}

// ---------------------------------------------------------------------------
extern "C" void kernel_launch(void* const* d_in, const int* in_sizes, int n_in,
                              void* d_out, int out_size, void* d_ws, size_t ws_size,
                              hipStream_t stream)
{
    const float* x  = (const float*)d_in[0];
    const float* y  = (const float*)d_in[1];
    const float* W1 = (const float*)d_in[2];
    const float* b1 = (const float*)d_in[3];
    const float* W2 = (const float*)d_in[4];
    const float* b2 = (const float*)d_in[5];
    float* outp = (float*)d_out;

    unsigned int* hx_h = (unsigned int*)d_ws;             // N_S*KP2 u32
    unsigned int* hy_h = hx_h + (size_t)N_S * KP2;        // N_S*KP2 u32
    float* partsum = (float*)(hy_h + (size_t)N_S * KP2);  // N_S f32
    float* diag = partsum + N_S;                          // N_S f32
    unsigned int* cnt = (unsigned int*)(diag + N_S);      // 1 u32

    gemm_h<<<320, 512, 0, stream>>>(x, y, W1, b1, hx_h, hy_h, partsum, cnt);

    pair_kernel<<<512, 256, 0, stream>>>(hx_h, hy_h, W2, b2,
                                         partsum, diag, cnt, outp);
}

// Round 16
// 43.174 us; speedup vs baseline: 1.0154x; 1.0154x over previous
//
#include <hip/hip_runtime.h>
#include <math.h>

#define N_S 1024
#define XD  768
#define LOW 300
#define KP  320     // f16 k-padding
#define KP2 160     // u32 (h2) per row

typedef _Float16 h2  __attribute__((ext_vector_type(2)));
typedef __fp16   g2  __attribute__((ext_vector_type(2)));
typedef _Float16 v8h __attribute__((ext_vector_type(8)));
typedef float    f4  __attribute__((ext_vector_type(4)));

union U32H2 { unsigned int u; h2 h; };
__device__ inline h2 u2h(unsigned int v){ U32H2 t; t.u = v; return t.h; }
__device__ inline unsigned int pk(float a, float b){
    g2 t = __builtin_amdgcn_cvt_pkrtz(a, b);
    return __builtin_bit_cast(unsigned int, t);
}
union U4V8 { uint4 u; v8h v; };

// ---------------------------------------------------------------------------
// Kernel 1: projection GEMM via MFMA f16 (r12-verified, unchanged). 320 jobs.
// Also zeroes partsum[1024] and cnt (visible to kernel 2 via stream order).
// ---------------------------------------------------------------------------
__global__ __launch_bounds__(512)
void gemm_h(const float* __restrict__ x, const float* __restrict__ y,
            const float* __restrict__ W1, const float* __restrict__ b1g,
            unsigned int* __restrict__ hx_h, unsigned int* __restrict__ hy_h,
            float* __restrict__ partsum, unsigned int* __restrict__ cnt)
{
    __shared__ unsigned int As[2][32][36];
    __shared__ unsigned int Bs[2][64][36];

    const int tid = threadIdx.x;
    const int job = blockIdx.x;
    if (job < 256 && tid < 4) partsum[job * 4 + tid] = 0.f;
    if (job == 0 && tid == 4) cnt[0] = 0u;

    const int which = job >= 160;
    const int t = which ? job - 160 : job;
    const int n0 = (t % 5) * 64;
    const int r0 = (t / 5) * 32;
    const float* A = which ? y : x;
    const float* W = W1 + (size_t)which * XD * LOW;
    _Float16* outh = (_Float16*)(which ? hy_h : hx_h);

    const int w = tid >> 6, l = tid & 63;
    const int wm = w >> 2, wn = w & 3;         // 2M x 4N
    const int lr = l & 15, lg = l >> 4;

    const int arow = tid >> 4, aq = tid & 15;  // A staging: 32 rows x 16 f4
    const int bn = tid & 63, bms = tid >> 6;   // B staging: 64 ncols x 8 m-grp
    const bool bin = (n0 + bn) < LOW;

    f4 acc = {};
    float4 a0; float bw[8];
    a0 = *(const float4*)&A[(size_t)(r0 + arow) * XD + aq * 4];
    #pragma unroll
    for (int s = 0; s < 8; ++s)
        bw[s] = bin ? W[(size_t)(bms * 8 + s) * LOW + n0 + bn] : 0.f;

    const int NC = XD / 64;                    // 12
    for (int c = 0; c < NC; ++c) {
        const int buf = c & 1;
        *(uint2*)&As[buf][arow][aq * 2] = make_uint2(pk(a0.x, a0.y), pk(a0.z, a0.w));
        *(uint4*)&Bs[buf][bn][bms * 4] =
            uint4{ pk(bw[0],bw[1]), pk(bw[2],bw[3]), pk(bw[4],bw[5]), pk(bw[6],bw[7]) };
        __syncthreads();
        if (c + 1 < NC) {
            const int kb = (c + 1) * 64;
            a0 = *(const float4*)&A[(size_t)(r0 + arow) * XD + kb + aq * 4];
            #pragma unroll
            for (int s = 0; s < 8; ++s)
                bw[s] = bin ? W[(size_t)(kb + bms * 8 + s) * LOW + n0 + bn] : 0.f;
        }
        #pragma unroll
        for (int ks = 0; ks < 2; ++ks) {
            const int ko = ks * 16 + lg * 4;
            U4V8 af; af.u = *(const uint4*)&As[buf][wm * 16 + lr][ko];
            U4V8 bf; bf.u = *(const uint4*)&Bs[buf][wn * 16 + lr][ko];
            acc = __builtin_amdgcn_mfma_f32_16x16x32_f16(af.v, bf.v, acc, 0, 0, 0);
        }
    }

    // D: col = l&15, row = 4*(l>>4)+r  (m89-verified)
    const int col = n0 + wn * 16 + lr;
    const float b1v = (which && col < LOW) ? b1g[col] : 0.f;
    #pragma unroll
    for (int r = 0; r < 4; ++r) {
        const int row = r0 + wm * 16 + lg * 4 + r;
        outh[(size_t)row * KP + col] = (_Float16)(acc[r] + b1v);
    }
}

// ---------------------------------------------------------------------------
// Kernel 2: pairwise critic, 512 thr = 8 waves, k-QUARTER split per lane
// group (kh = tid bits 4-5), 4i x 4j per thread, natural [row][k] LDS.
//   s[i][j] = sum_k relu(hy[i,k]+hx[j,k])*w2[k] + b2
//   partsum[i] += sum_j e^s  (exp(softplus)=1+e^s);  diag[i]=softplus(s[i,i])
// Tile 32(i) x 64(j); wave w handles rows i0+w*4..+3 (ya reads broadcast).
// 2 blocks/CU x 8 waves = 4 waves/SIMD (2x all prior variants) -- the one
// axis not yet tested. k-quarters combined with shfl_xor 16,32.
// 512 blocks (XCD-swizzled), atomic finish (r12-verified).
// ---------------------------------------------------------------------------
__global__ __launch_bounds__(512)
void pair_kernel(const unsigned int* __restrict__ hx_h, const unsigned int* __restrict__ hy_h,
                 const float* __restrict__ W2, const float* __restrict__ b2,
                 float* __restrict__ partsum, float* __restrict__ diag,
                 unsigned int* __restrict__ cnt, float* __restrict__ out)
{
    const int b0 = blockIdx.x;
    const int bs = (b0 & 7) * 64 + (b0 >> 3);   // XCD swizzle (512%8==0)
    const int jb = bs & 15, ib = bs >> 4;       // 16 j-tiles x 32 i-tiles
    const int j0 = jb * 64, i0 = ib * 32;

    __shared__ unsigned int Hy[32][164];        // [i][k/2], 656B rows (16B-al)
    __shared__ unsigned int Hx[64][164];        // [j][k/2]
    __shared__ unsigned int w2s[KP2];
    __shared__ unsigned int lastFlag;
    __shared__ float ssum[8];

    const int tid = threadIdx.x;

    // ---- stage Hy: 1280 uint4 over 512 thr (e<3 guarded) ----
    {
        const int r = tid >> 4, sq = tid & 15;
        const unsigned int* sy = &hy_h[(size_t)(i0 + r) * KP2];
        #pragma unroll
        for (int e = 0; e < 3; ++e) {
            const int s = sq + 16 * e;
            if (s < 40)
                *(uint4*)&Hy[r][s * 4] = *(const uint4*)&sy[s * 4];
        }
    }
    // ---- stage Hx: 2560 uint4, exactly 5 per thread ----
    {
        const int r = tid >> 3, sq = tid & 7;
        const unsigned int* sx = &hx_h[(size_t)(j0 + r) * KP2];
        #pragma unroll
        for (int e = 0; e < 5; ++e) {
            const int s = sq + 8 * e;
            *(uint4*)&Hx[r][s * 4] = *(const uint4*)&sx[s * 4];
        }
    }
    if (tid < KP2) {
        int k = tid * 2;
        float w0 = (k < LOW) ? W2[k] : 0.f;
        float w1 = (k + 1 < LOW) ? W2[k + 1] : 0.f;
        w2s[tid] = pk(w0, w1);
    }
    __syncthreads();

    const int tx = tid & 15;           // j = j0 + tx*4 + q
    const int kh = (tid >> 4) & 3;     // k-quarter (lane bits 4-5)
    const int iy = tid >> 6;           // wave id -> rows i0+iy*4..+3

    float acc[4][4] = {};
    const h2 hz = h2{(_Float16)0.f, (_Float16)0.f};
    const int tb = kh * 10;            // 40 t-iters total; 10 per quarter

    #pragma unroll 2
    for (int ti = 0; ti < 10; ++ti) {
        const int t = tb + ti;
        uint4 ya[4], xb[4];
        #pragma unroll
        for (int r = 0; r < 4; ++r)
            ya[r] = *(const uint4*)&Hy[iy * 4 + r][t * 4];   // wave-broadcast
        #pragma unroll
        for (int q = 0; q < 4; ++q)
            xb[q] = *(const uint4*)&Hx[tx * 4 + q][t * 4];   // 2-way max
        const uint4 wv = *(const uint4*)&w2s[t * 4];
        const unsigned int wve[4] = {wv.x, wv.y, wv.z, wv.w};
        #pragma unroll
        for (int e = 0; e < 4; ++e) {
            const h2 w = u2h(wve[e]);
            const unsigned int yae[4] = {ya[0][e], ya[1][e], ya[2][e], ya[3][e]};
            const unsigned int xbe[4] = {xb[0][e], xb[1][e], xb[2][e], xb[3][e]};
            #pragma unroll
            for (int r = 0; r < 4; ++r) {
                const h2 a = u2h(yae[r]);
                #pragma unroll
                for (int q = 0; q < 4; ++q) {
                    h2 z = __builtin_elementwise_max(a + u2h(xbe[q]), hz);
                    acc[r][q] = __builtin_amdgcn_fdot2(z, w, acc[r][q], false);
                }
            }
        }
    }

    // combine 4 k-quarters (lane bits 4-5)
    #pragma unroll
    for (int r = 0; r < 4; ++r)
        #pragma unroll
        for (int q = 0; q < 4; ++q) {
            float v = acc[r][q];
            v += __shfl_xor(v, 16, 64);
            v += __shfl_xor(v, 32, 64);
            acc[r][q] = v;
        }

    const float b2v = b2[0];
    #pragma unroll
    for (int r = 0; r < 4; ++r) {
        const int row = i0 + iy * 4 + r;
        float es = 0.f;
        #pragma unroll
        for (int q = 0; q < 4; ++q) {
            const float s = acc[r][q] + b2v;
            es += __expf(s);                     // exp(softplus) = 1 + e^s
            const int col = j0 + tx * 4 + q;
            if (col == row)
                atomicExch(&diag[row],           // dup lanes write same value
                           fmaxf(s, 0.f) + __logf(1.f + __expf(-fabsf(s))));
        }
        #pragma unroll
        for (int o = 1; o <= 8; o <<= 1) es += __shfl_xor(es, o, 64);
        if ((tid & 63) == 0) atomicAdd(&partsum[row], es);   // 1 add/row
    }

    // ---- completion: drain atomics, count blocks, last block reduces ----
    asm volatile("s_waitcnt vmcnt(0)" ::: "memory");
    __syncthreads();
    if (tid == 0) lastFlag = (atomicAdd(cnt, 1u) == 511u) ? 1u : 0u;
    __syncthreads();
    if (!lastFlag) return;

    float csum = 0.f;
    #pragma unroll
    for (int g = 0; g < 2; ++g) {
        const int row = g * 512 + tid;
        const float ps = atomicAdd(&partsum[row], 0.f);   // coherent read
        const float dg = atomicAdd(&diag[row], 0.f);      // coherent read
        csum += dg - __logf((float)N_S + ps);
    }
    #pragma unroll
    for (int o = 32; o > 0; o >>= 1) csum += __shfl_xor(csum, o, 64);
    if ((tid & 63) == 0) ssum[tid >> 6] = csum;
    __syncthreads();
    if (tid == 0) {
        float t = 0.f;
        #pragma unroll
        for (int q = 0; q < 8; ++q) t += ssum[q];
        out[0] = t * (1.0f / N_S) - logf((float)N_S);
    }
}

// ---------------------------------------------------------------------------
extern "C" void kernel_launch(void* const* d_in, const int* in_sizes, int n_in,
                              void* d_out, int out_size, void* d_ws, size_t ws_size,
                              hipStream_t stream)
{
    const float* x  = (const float*)d_in[0];
    const float* y  = (const float*)d_in[1];
    const float* W1 = (const float*)d_in[2];
    const float* b1 = (const float*)d_in[3];
    const float* W2 = (const float*)d_in[4];
    const float* b2 = (const float*)d_in[5];
    float* outp = (float*)d_out;

    unsigned int* hx_h = (unsigned int*)d_ws;             // N_S*KP2 u32
    unsigned int* hy_h = hx_h + (size_t)N_S * KP2;        // N_S*KP2 u32
    float* partsum = (float*)(hy_h + (size_t)N_S * KP2);  // N_S f32
    float* diag = partsum + N_S;                          // N_S f32
    unsigned int* cnt = (unsigned int*)(diag + N_S);      // 1 u32

    gemm_h<<<320, 512, 0, stream>>>(x, y, W1, b1, hx_h, hy_h, partsum, cnt);

    pair_kernel<<<512, 512, 0, stream>>>(hx_h, hy_h, W2, b2,
                                         partsum, diag, cnt, outp);
}